// Round 1
// baseline (235.651 us; speedup 1.0000x reference)
//
#include <hip/hip_runtime.h>
#include <math.h>

// EntropyLoss: heatmap [8, 20, 512, 512] f32 -> entropy [8] f32
//
// Per (n,c): masked (x>0) softmax entropy, computed WITHOUT the max pass:
//   s = sum_{x>0} e^x,  t = sum_{x>0} x*e^x,  ent_nats = log(s) - t/s
// (identical to reference algebra; x in ~(0,6] so e^x <= ~400, no overflow).
// Output: out[n] = (sum_c ent_nats / ln2) / (total positive count over c).

#define NCH 160      // N*C = 8*20
#define HW  262144   // 512*512
#define BPC 64       // blocks per channel
#define TPB 256

// ws layout: [0,160)=sumE  [160,320)=sumXE  [320,480)=count
__global__ void init_ws_kernel(float* ws) {
    int i = threadIdx.x;
    if (i < 3 * NCH) ws[i] = 0.0f;
}

__global__ __launch_bounds__(TPB) void entropy_partial_kernel(
        const float* __restrict__ x, float* __restrict__ ws) {
    const int ch   = blockIdx.x / BPC;
    const int part = blockIdx.x % BPC;
    const float4* base =
        (const float4*)(x + (size_t)ch * HW + (size_t)part * (HW / BPC));
    // HW/BPC = 4096 floats = 1024 float4 = 256 threads * 4 float4

    float sumE = 0.0f, sumXE = 0.0f, fcnt = 0.0f;
#pragma unroll
    for (int t = 0; t < 4; ++t) {
        float4 v = base[threadIdx.x + t * TPB];
        float vals[4] = {v.x, v.y, v.z, v.w};
#pragma unroll
        for (int j = 0; j < 4; ++j) {
            float xv = vals[j];
            float e  = __expf(xv);          // always computed; predicated accum
            if (xv > 0.0f) {
                sumE  += e;
                sumXE += xv * e;
                fcnt  += 1.0f;
            }
        }
    }

    // wave64 butterfly-free shuffle-down reduction
#pragma unroll
    for (int off = 32; off > 0; off >>= 1) {
        sumE  += __shfl_down(sumE,  off, 64);
        sumXE += __shfl_down(sumXE, off, 64);
        fcnt  += __shfl_down(fcnt,  off, 64);
    }

    __shared__ float sE[4], sXE[4], sC[4];
    const int wave = threadIdx.x >> 6;
    const int lane = threadIdx.x & 63;
    if (lane == 0) { sE[wave] = sumE; sXE[wave] = sumXE; sC[wave] = fcnt; }
    __syncthreads();
    if (threadIdx.x == 0) {
        float tE  = sE[0] + sE[1] + sE[2] + sE[3];
        float tXE = sXE[0] + sXE[1] + sXE[2] + sXE[3];
        float tC  = sC[0] + sC[1] + sC[2] + sC[3];
        atomicAdd(&ws[ch], tE);
        atomicAdd(&ws[NCH + ch], tXE);
        atomicAdd(&ws[2 * NCH + ch], tC);
    }
}

__global__ void entropy_final_kernel(const float* __restrict__ ws,
                                     float* __restrict__ out) {
    __shared__ float ent[NCH], cnts[NCH];
    const int i = threadIdx.x;
    if (i < NCH) {
        float s = ws[i];
        float t = ws[NCH + i];
        float e = 0.0f;
        if (s > 0.0f) e = logf(s) - t / s;   // nats
        ent[i]  = e;
        cnts[i] = ws[2 * NCH + i];
    }
    __syncthreads();
    if (i < 8) {
        float se = 0.0f, sc = 0.0f;
#pragma unroll
        for (int c = 0; c < 20; ++c) {
            se += ent[i * 20 + c];
            sc += cnts[i * 20 + c];
        }
        out[i] = (se / 0.6931471805599453f) / sc;   // bits / point_count
    }
}

extern "C" void kernel_launch(void* const* d_in, const int* in_sizes, int n_in,
                              void* d_out, int out_size, void* d_ws, size_t ws_size,
                              hipStream_t stream) {
    const float* heatmap = (const float*)d_in[0];
    float* out = (float*)d_out;
    float* ws  = (float*)d_ws;

    hipLaunchKernelGGL(init_ws_kernel, dim3(1), dim3(512), 0, stream, ws);
    hipLaunchKernelGGL(entropy_partial_kernel, dim3(NCH * BPC), dim3(TPB), 0, stream,
                       heatmap, ws);
    hipLaunchKernelGGL(entropy_final_kernel, dim3(1), dim3(256), 0, stream, ws, out);
}

// Round 2
// 227.860 us; speedup vs baseline: 1.0342x; 1.0342x over previous
//
#include <hip/hip_runtime.h>
#include <math.h>

// EntropyLoss: heatmap [8, 20, 512, 512] f32 -> entropy [8] f32
//
// Per (n,c): masked (x>0) softmax entropy without the max pass:
//   s = sum_{x>0} e^x,  t = sum_{x>0} x*e^x,  ent_nats = log(s) - t/s
// (algebraically identical to the reference; x <= ~6 so e^x <= ~400, no
// overflow in f32). out[n] = (sum_c ent_nats / ln2) / (positive count).
//
// Two dispatches, no init kernel, no atomics:
//   partial: per-block partial sums STORED (poison-safe, ws never read
//            before written) into SoA layout ws[part*NCH + ch] so the
//            final kernel's per-thread reads coalesce across channels.
//   final:   one block; 64 partials/channel reduce + channel->n reduce.

#define NCH 160      // N*C = 8*20
#define HW  262144   // 512*512
#define BPC 64       // blocks per channel
#define TPB 256
#define NPART (NCH * BPC)   // 10240 partials per quantity

__global__ __launch_bounds__(TPB) void entropy_partial_kernel(
        const float* __restrict__ x, float* __restrict__ ws) {
    const int ch   = blockIdx.x / BPC;
    const int part = blockIdx.x % BPC;
    const float4* base =
        (const float4*)(x + (size_t)ch * HW + (size_t)part * (HW / BPC));
    // HW/BPC = 4096 floats = 1024 float4 = 256 threads * 4 float4

    float sumE = 0.0f, sumXE = 0.0f, fcnt = 0.0f;
#pragma unroll
    for (int t = 0; t < 4; ++t) {
        float4 v = base[threadIdx.x + t * TPB];
        float vals[4] = {v.x, v.y, v.z, v.w};
#pragma unroll
        for (int j = 0; j < 4; ++j) {
            float xv = vals[j];
            float e  = __expf(xv);
            if (xv > 0.0f) {
                sumE  += e;
                sumXE += xv * e;
                fcnt  += 1.0f;
            }
        }
    }

    // wave64 shuffle reduction
#pragma unroll
    for (int off = 32; off > 0; off >>= 1) {
        sumE  += __shfl_down(sumE,  off, 64);
        sumXE += __shfl_down(sumXE, off, 64);
        fcnt  += __shfl_down(fcnt,  off, 64);
    }

    __shared__ float sE[4], sXE[4], sC[4];
    const int wave = threadIdx.x >> 6;
    const int lane = threadIdx.x & 63;
    if (lane == 0) { sE[wave] = sumE; sXE[wave] = sumXE; sC[wave] = fcnt; }
    __syncthreads();
    if (threadIdx.x == 0) {
        const int slot = part * NCH + ch;   // ch fastest -> coalesced in final
        ws[slot]             = sE[0] + sE[1] + sE[2] + sE[3];
        ws[NPART + slot]     = sXE[0] + sXE[1] + sXE[2] + sXE[3];
        ws[2 * NPART + slot] = sC[0] + sC[1] + sC[2] + sC[3];
    }
}

__global__ __launch_bounds__(TPB) void entropy_final_kernel(
        const float* __restrict__ ws, float* __restrict__ out) {
    __shared__ float ent[NCH], cnts[NCH];
    const int i = threadIdx.x;
    if (i < NCH) {
        float s = 0.0f, t = 0.0f, c = 0.0f;
#pragma unroll 8
        for (int p = 0; p < BPC; ++p) {
            s += ws[p * NCH + i];                 // coalesced across threads
            t += ws[NPART + p * NCH + i];
            c += ws[2 * NPART + p * NCH + i];
        }
        float e = 0.0f;
        if (s > 0.0f) e = logf(s) - t / s;        // nats
        ent[i]  = e;
        cnts[i] = c;
    }
    __syncthreads();
    if (i < 8) {
        float se = 0.0f, sc = 0.0f;
#pragma unroll
        for (int c = 0; c < 20; ++c) {
            se += ent[i * 20 + c];
            sc += cnts[i * 20 + c];
        }
        out[i] = (se / 0.6931471805599453f) / sc;  // bits / point_count
    }
}

extern "C" void kernel_launch(void* const* d_in, const int* in_sizes, int n_in,
                              void* d_out, int out_size, void* d_ws, size_t ws_size,
                              hipStream_t stream) {
    const float* heatmap = (const float*)d_in[0];
    float* out = (float*)d_out;
    float* ws  = (float*)d_ws;

    hipLaunchKernelGGL(entropy_partial_kernel, dim3(NCH * BPC), dim3(TPB), 0,
                       stream, heatmap, ws);
    hipLaunchKernelGGL(entropy_final_kernel, dim3(1), dim3(TPB), 0, stream,
                       ws, out);
}

// Round 4
// 213.857 us; speedup vs baseline: 1.1019x; 1.0655x over previous
//
#include <hip/hip_runtime.h>
#include <math.h>

// EntropyLoss: heatmap [8, 20, 512, 512] f32 -> entropy [8] f32
//
// Per (n,c): masked (x>0) softmax entropy without the max pass:
//   s = sum_{x>0} e^x,  t = sum_{x>0} x*e^x,  ent_nats = log(s) - t/s
// (algebraically identical to the reference; x <= ~6 so e^x <= ~400, no
// overflow in f32). out[n] = (sum_c ent_nats / ln2) / (positive count).
//
// Two dispatches, no init, no atomics. Partial results are STORED
// (poison-safe) in SoA layout ws[part*NCH + ch] for coalesced final reads.
// BPC=32: each partial block streams 8192 floats (8 float4/thread, 8
// outstanding loads), halving partial-store + final-read traffic vs BPC=64.
// Input loads are non-temporal (read-once stream; don't thrash L2).
// NOTE: __builtin_nontemporal_load needs a clang native vector type, not
// HIP's float4 struct — hence v4f below.

#define NCH 160      // N*C = 8*20
#define HW  262144   // 512*512
#define BPC 32       // blocks per channel
#define TPB 256
#define VPT 8        // float4 per thread: 8*4*256 = 8192 floats = HW/BPC
#define NPART (NCH * BPC)   // 5120 partials per quantity

typedef float v4f __attribute__((ext_vector_type(4)));

__global__ __launch_bounds__(TPB) void entropy_partial_kernel(
        const float* __restrict__ x, float* __restrict__ ws) {
    const int ch   = blockIdx.x / BPC;
    const int part = blockIdx.x % BPC;
    const v4f* base =
        (const v4f*)(x + (size_t)ch * HW + (size_t)part * (HW / BPC));

    float sumE = 0.0f, sumXE = 0.0f, fcnt = 0.0f;
#pragma unroll
    for (int t = 0; t < VPT; ++t) {
        v4f v = __builtin_nontemporal_load(&base[threadIdx.x + t * TPB]);
#pragma unroll
        for (int j = 0; j < 4; ++j) {
            float xv = v[j];
            float e  = __expf(xv);
            if (xv > 0.0f) {
                sumE  += e;
                sumXE += xv * e;
                fcnt  += 1.0f;
            }
        }
    }

    // wave64 shuffle reduction
#pragma unroll
    for (int off = 32; off > 0; off >>= 1) {
        sumE  += __shfl_down(sumE,  off, 64);
        sumXE += __shfl_down(sumXE, off, 64);
        fcnt  += __shfl_down(fcnt,  off, 64);
    }

    __shared__ float sE[4], sXE[4], sC[4];
    const int wave = threadIdx.x >> 6;
    const int lane = threadIdx.x & 63;
    if (lane == 0) { sE[wave] = sumE; sXE[wave] = sumXE; sC[wave] = fcnt; }
    __syncthreads();
    if (threadIdx.x == 0) {
        const int slot = part * NCH + ch;   // ch fastest -> coalesced in final
        ws[slot]             = sE[0] + sE[1] + sE[2] + sE[3];
        ws[NPART + slot]     = sXE[0] + sXE[1] + sXE[2] + sXE[3];
        ws[2 * NPART + slot] = sC[0] + sC[1] + sC[2] + sC[3];
    }
}

__global__ __launch_bounds__(TPB) void entropy_final_kernel(
        const float* __restrict__ ws, float* __restrict__ out) {
    __shared__ float ent[NCH], cnts[NCH];
    const int i = threadIdx.x;
    if (i < NCH) {
        float s = 0.0f, t = 0.0f, c = 0.0f;
#pragma unroll 8
        for (int p = 0; p < BPC; ++p) {
            s += ws[p * NCH + i];                 // coalesced across threads
            t += ws[NPART + p * NCH + i];
            c += ws[2 * NPART + p * NCH + i];
        }
        float e = 0.0f;
        if (s > 0.0f) e = logf(s) - t / s;        // nats
        ent[i]  = e;
        cnts[i] = c;
    }
    __syncthreads();
    if (i < 8) {
        float se = 0.0f, sc = 0.0f;
#pragma unroll
        for (int c = 0; c < 20; ++c) {
            se += ent[i * 20 + c];
            sc += cnts[i * 20 + c];
        }
        out[i] = (se / 0.6931471805599453f) / sc;  // bits / point_count
    }
}

extern "C" void kernel_launch(void* const* d_in, const int* in_sizes, int n_in,
                              void* d_out, int out_size, void* d_ws, size_t ws_size,
                              hipStream_t stream) {
    const float* heatmap = (const float*)d_in[0];
    float* out = (float*)d_out;
    float* ws  = (float*)d_ws;

    hipLaunchKernelGGL(entropy_partial_kernel, dim3(NCH * BPC), dim3(TPB), 0,
                       stream, heatmap, ws);
    hipLaunchKernelGGL(entropy_final_kernel, dim3(1), dim3(TPB), 0, stream,
                       ws, out);
}